// Round 20
// baseline (116.976 us; speedup 1.0000x reference)
//
#include <hip/hip_runtime.h>
#include <stdint.h>

typedef short bf16x8 __attribute__((ext_vector_type(8)));
typedef float f32x4 __attribute__((ext_vector_type(4)));
typedef uint16_t u16;
typedef uint32_t u32;
typedef u16 u16x4 __attribute__((ext_vector_type(4)));
typedef u32 u32x4 __attribute__((ext_vector_type(4)));

#define EPSF 1.1920929e-07f

static __device__ __forceinline__ u16 f2bf(float f) {
  union { float f; uint32_t u; } v; v.f = f;
  return (u16)((v.u + 0x7FFFu + ((v.u >> 16) & 1u)) >> 16);  // RNE
}
static __device__ __forceinline__ float bf2f(u16 h) {
  union { uint32_t u; float f; } v; v.u = ((uint32_t)h) << 16;
  return v.f;
}
static __device__ __forceinline__ float exp2_fast(float x) {
  return __builtin_amdgcn_exp2f(x);  // v_exp_f32: D = 2^S0
}
static __device__ __forceinline__ u32 cvt_pk_bf16(float lo, float hi) {
  u32 r;
  asm("v_cvt_pk_bf16_f32 %0, %1, %2" : "=v"(r) : "v"(lo), "v"(hi));
  return r;
}
static __device__ __forceinline__ void gload_lds16(const void* g, void* l) {
  __builtin_amdgcn_global_load_lds(
      (const __attribute__((address_space(1))) void*)g,
      (__attribute__((address_space(3))) void*)l, 16, 0, 0);
}
template <int N>
static __device__ __forceinline__ void vmwait() {
  asm volatile("s_waitcnt vmcnt(%0)" ::"i"(N) : "memory");
}

// ---------------------------------------------------------------------------
// 1) prep: fake-quant (blocks 0..4095) + x -> plain bf16 (blocks 4096..8191).
// ---------------------------------------------------------------------------
__global__ __launch_bounds__(256) void prep_kernel(
    const float* __restrict__ wq, const float* __restrict__ wk,
    const float* __restrict__ wv, const float* __restrict__ wp,
    const float* __restrict__ x,
    u16* __restrict__ wout, float* __restrict__ scales, u16* __restrict__ xb) {
  const int t = threadIdx.x;
  if (blockIdx.x < 4096) {
    const int row = blockIdx.x & 1023;
    const int mat = blockIdx.x >> 10;
    const float* W = (mat == 0) ? wq : (mat == 1) ? wk : (mat == 2) ? wv : wp;
    const float4 v = ((const float4*)(W + (size_t)row * 1024))[t];
    float m = fmaxf(fmaxf(fabsf(v.x), fabsf(v.y)), fmaxf(fabsf(v.z), fabsf(v.w)));
#pragma unroll
    for (int off = 1; off < 64; off <<= 1) m = fmaxf(m, __shfl_xor(m, off));
    __shared__ float red[4];
    if ((t & 63) == 0) red[t >> 6] = m;
    __syncthreads();
    m = fmaxf(fmaxf(red[0], red[1]), fmaxf(red[2], red[3]));
    const float scale = fmaxf(m / 127.0f, EPSF);
    float q0 = fminf(fmaxf(rintf(v.x / scale), -127.f), 127.f);
    float q1 = fminf(fmaxf(rintf(v.y / scale), -127.f), 127.f);
    float q2 = fminf(fmaxf(rintf(v.z / scale), -127.f), 127.f);
    float q3 = fminf(fmaxf(rintf(v.w / scale), -127.f), 127.f);
    u16x4 o; o.x = f2bf(q0); o.y = f2bf(q1); o.z = f2bf(q2); o.w = f2bf(q3);
    *(u16x4*)(wout + ((size_t)(mat * 1024 + row)) * 1024 + t * 4) = o;
    if (t == 0) scales[mat * 1024 + row] = scale;
  } else {
    const int i = (blockIdx.x - 4096) * 256 + t;  // quad index
    const float4 v = ((const float4*)x)[i];
    u16x4 hv;
    hv.x = f2bf(v.x); hv.y = f2bf(v.y); hv.z = f2bf(v.z); hv.w = f2bf(v.w);
    *(u16x4*)(xb + (size_t)i * 4) = hv;  // [4096][1024] row-major
  }
}

// ---------------------------------------------------------------------------
// 3) bf16 MFMA GEMM, counted-vmcnt pipeline. MODE 0: V written SIGMA-PACKED
//    per-bh ([64 d][2048 k], each 32-k chunk reordered pos = l4k*8+hi*4+j
//    for k = hi*16+l4k*4+j) so attn's PV B-fragment is one contiguous b128.
// ---------------------------------------------------------------------------
template <int MODE, int MR, int NR, int NT, int KT, int LDA>
__global__ __launch_bounds__(512) void gemm_kernel(
    const u16* __restrict__ A, const u16* __restrict__ Bw,
    const float* __restrict__ scales, const float* __restrict__ b0,
    const float* __restrict__ b1, const float* __restrict__ b2,
    u16* __restrict__ qkv, float* __restrict__ outp) {
  constexpr int BM = 2 * MR * 16;
  constexpr int BN = 4 * NR * 16;
  constexpr int OPS = BM / 64 + BN / 64;  // gload_lds per thread per K-tile
  __shared__ u16 As[2][BM * 64];
  __shared__ u16 Bs[2][BN * 64];
  const int tid = threadIdx.x;
  const int w = tid >> 6, l = tid & 63;
  const int per = gridDim.x >> 3;
  const int L = (blockIdx.x & 7) * per + (blockIdx.x >> 3);
  const int tile_n = (L % NT) * BN;
  const int tile_m = (L / NT) * BM;
  const int wm = w >> 2, wn = w & 3;
  const int l15 = l & 15, l4 = l >> 4;
  const int sw = l15 & 7;

  f32x4 acc[MR][NR];
  const f32x4 vzero = {0.f, 0.f, 0.f, 0.f};
#pragma unroll
  for (int m = 0; m < MR; ++m)
#pragma unroll
    for (int n = 0; n < NR; ++n) acc[m][n] = vzero;

  const int r8 = tid >> 3;          // 0..63
  const int g = tid & 7;
  const int gs = g ^ (r8 & 7);      // pre-swizzled source granule
  auto STAGE = [&](int slot, int j) {
    const int kb = j * 64;
    const int kbB = kb & 1023;
#pragma unroll
    for (int i = 0; i < BM / 64; ++i)
      gload_lds16(A + (size_t)(tile_m + i * 64 + r8) * LDA + kb + gs * 8,
                  &As[slot][(i * 64 + r8) * 64 + g * 8]);
#pragma unroll
    for (int i = 0; i < BN / 64; ++i)
      gload_lds16(Bw + (size_t)(tile_n + i * 64 + r8) * 1024 + kbB + gs * 8,
                  &Bs[slot][(i * 64 + r8) * 64 + g * 8]);
  };

  STAGE(0, 0);
  STAGE(1, 1);
  vmwait<OPS>();                      // K0 landed; K1 still in flight
  __builtin_amdgcn_s_barrier();

  for (int j = 0; j < KT; ++j) {
    const int cur = j & 1;
#pragma unroll
    for (int ks = 0; ks < 2; ++ks) {
      bf16x8 af[MR], bfv[NR];
      const int sg8 = ((ks * 4 + l4) ^ sw) * 8;
#pragma unroll
      for (int m = 0; m < MR; ++m)
        af[m] = *(const bf16x8*)(&As[cur][(wm * (MR * 16) + m * 16 + l15) * 64 + sg8]);
#pragma unroll
      for (int n = 0; n < NR; ++n)
        bfv[n] = *(const bf16x8*)(&Bs[cur][(wn * (NR * 16) + n * 16 + l15) * 64 + sg8]);
      __builtin_amdgcn_s_setprio(1);
#pragma unroll
      for (int m = 0; m < MR; ++m)
#pragma unroll
        for (int n = 0; n < NR; ++n)
          acc[m][n] = __builtin_amdgcn_mfma_f32_16x16x32_bf16(af[m], bfv[n], acc[m][n], 0, 0, 0);
      __builtin_amdgcn_s_setprio(0);
    }
    __builtin_amdgcn_s_barrier();     // all waves done reading slot cur
    if (j + 2 < KT) {
      STAGE(cur, j + 2);
      vmwait<OPS>();                  // K_{j+1} landed; K_{j+2} in flight
    } else {
      vmwait<0>();
    }
    __builtin_amdgcn_s_barrier();     // K_{j+1} visible to all waves
  }

#pragma unroll
  for (int m = 0; m < MR; ++m) {
#pragma unroll
    for (int n = 0; n < NR; ++n) {
      const int col = tile_n + wn * (NR * 16) + n * 16 + l15;
      const float sc = scales[col];
      if constexpr (MODE == 0) {
        const int mat = col >> 10, oo = col & 1023;
        const float* bias = (mat == 0) ? b0 : (mat == 1) ? b1 : b2;
        const float bb = bias[oo];
        const int hh = oo >> 6, dd = oo & 63;
        if (mat == 2) {
          // V' sigma-packed: [bh][64 d][2048 k']; within each 32-k chunk,
          // pos = ((k>>2)&3)*8 + ((k>>4)&1)*4 + (k&3). The lane's 4
          // consecutive k (s0..s0+3, s0%4==0) stay one contiguous u16x4.
          const int rowm0 = tile_m + wm * (MR * 16) + m * 16 + l4 * 4;
          const int b = rowm0 >> 11, s = rowm0 & 2047;
          u16x4 pk;
#pragma unroll
          for (int jj = 0; jj < 4; ++jj) pk[jj] = f2bf(acc[m][n][jj] * sc + bb);
          const int kpos = (s & ~31) + ((s >> 2) & 3) * 8 + ((s >> 4) & 1) * 4;
          *(u16x4*)(qkv + (size_t)2 * 4194304 +
                    ((size_t)(b * 16 + hh) * 64 + dd) * 2048 + kpos) = pk;
        } else {
#pragma unroll
          for (int jj = 0; jj < 4; ++jj) {
            const int rowm = tile_m + wm * (MR * 16) + m * 16 + l4 * 4 + jj;
            const int b = rowm >> 11, s = rowm & 2047;
            float y = acc[m][n][jj] * sc + bb;
            if (mat == 0) y *= 0.18033688011112042f;  // 0.125*log2(e)
            qkv[(size_t)mat * 4194304 + ((size_t)(b * 16 + hh) * 2048 + s) * 64 + dd] = f2bf(y);
          }
        }
      } else {
        const float bb = b0[col];
#pragma unroll
        for (int jj = 0; jj < 4; ++jj) {
          const int rowm = tile_m + wm * (MR * 16) + m * 16 + l4 * 4 + jj;
          outp[(size_t)rowm * 1024 + col] = acc[m][n][jj] * sc + bb;
        }
      }
    }
  }
}

// ---------------------------------------------------------------------------
// 4) Flash attention v16: KV-split x WIDE-Q waves. 256 threads = 2 groups x
//    2 waves x 64 q (4 q-frags/wave): kf/vf register-shared across 4 q-frags
//    -> per-CU LDS b128 count HALVES vs R19 (the dominant pipe at 45%).
//    KVBLK=64/group, R17's two-barrier distance-2 counted-vmcnt schedule,
//    sigma-packed V (one b128 per PV fragment), no-max exp2 softmax,
//    XCD-chunk swizzle. __launch_bounds__(256,2): 256-VGPR budget (LDS 64KB
//    caps at 2 blocks/CU anyway). Parallel cross-spill merge epilogue.
// ---------------------------------------------------------------------------
__global__ __launch_bounds__(256, 2) void attn_kernel(
    const u16* __restrict__ qg, const u16* __restrict__ kg,
    const u16* __restrict__ vtg, u16* __restrict__ po) {
  __shared__ u16 Kt[2][2][64 * 64];     // [slot][group][k][d], swizzled
  __shared__ u16 Vt[2][2][64 * 64];     // [slot][group][d][k'], swizzled
  const int tid = threadIdx.x;
  const int w = tid >> 6, l = tid & 63;
  const int Lb = (blockIdx.x & 7) * 64 + (blockIdx.x >> 3);  // XCD chunk
  const int bh = Lb >> 4;
  const int qt = Lb & 15;
  const u16* qp = qg + (size_t)bh * 131072;
  const u16* kp = kg + (size_t)bh * 131072;
  const u16* vp = vtg + (size_t)bh * 131072;  // V' [64][2048] sigma-packed
  const int wg = w & 1, grp = w >> 1;
  const int qrow0 = qt * 128 + wg * 64;
  const int l15 = l & 15, l4 = l >> 4;
  const int sw = l15 & 7;

  // stage both groups' K/V tiles; linear LDS dest, swizzled GLOBAL source
  auto STAGE = [&](const int slot, const int j) {
    const int kA = j * 64, kB = 1024 + j * 64;
#pragma unroll
    for (int i = 0; i < 2; ++i) {
      const int c = i * 256 + tid;      // 0..511 chunks of 16B
      const int r = c >> 3, g = c & 7;
      const int gg = (g ^ (r & 7)) << 3;
      gload_lds16(kp + (size_t)(kA + r) * 64 + gg, &Kt[slot][0][c * 8]);
      gload_lds16(vp + (size_t)r * 2048 + kA + gg, &Vt[slot][0][c * 8]);
      gload_lds16(kp + (size_t)(kB + r) * 64 + gg, &Kt[slot][1][c * 8]);
      gload_lds16(vp + (size_t)r * 2048 + kB + gg, &Vt[slot][1][c * 8]);
    }
  };

  bf16x8 qfr[2][4];  // [dk][qf]
#pragma unroll
  for (int dk = 0; dk < 2; ++dk)
#pragma unroll
    for (int qf = 0; qf < 4; ++qf)
      qfr[dk][qf] =
          *(const bf16x8*)(qp + (size_t)(qrow0 + qf * 16 + l15) * 64 + dk * 32 + l4 * 8);

  const f32x4 vzero = {0.f, 0.f, 0.f, 0.f};
  f32x4 O[4][4];  // [di][qf]
#pragma unroll
  for (int di = 0; di < 4; ++di)
#pragma unroll
    for (int qf = 0; qf < 4; ++qf) O[di][qf] = vzero;
  float lrun[4] = {0.f, 0.f, 0.f, 0.f};

  // one iteration per group-local 64-k tile; slot LITERAL at call sites
  auto DO_ITER = [&](const int slot, const int j) {
    const u16* Kb = &Kt[slot][grp][0];
    const u16* Vb = &Vt[slot][grp][0];

    // S^T = K Q^T over 64 k: D[k][q], k = ki*16 + l4*4 + jj, q = l15 (+qf*16)
    f32x4 sfr[4][4];  // [qf][ki]
#pragma unroll
    for (int qf = 0; qf < 4; ++qf)
#pragma unroll
      for (int ki = 0; ki < 4; ++ki) sfr[qf][ki] = vzero;
#pragma unroll
    for (int dk = 0; dk < 2; ++dk) {
      bf16x8 kf[4];
#pragma unroll
      for (int ki = 0; ki < 4; ++ki)
        kf[ki] = *(const bf16x8*)(Kb + (ki * 16 + l15) * 64 + (((dk * 4 + l4) ^ sw) << 3));
      __builtin_amdgcn_s_setprio(1);
#pragma unroll
      for (int ki = 0; ki < 4; ++ki)
#pragma unroll
        for (int qf = 0; qf < 4; ++qf)
          sfr[qf][ki] = __builtin_amdgcn_mfma_f32_16x16x32_bf16(kf[ki], qfr[dk][qf], sfr[qf][ki], 0, 0, 0);
      __builtin_amdgcn_s_setprio(0);
    }

    // no-max softmax: p = exp2(S); P stays in registers
    u32 pw[4][8];
#pragma unroll
    for (int qf = 0; qf < 4; ++qf) {
      float rs = 0.f;
#pragma unroll
      for (int ki = 0; ki < 4; ++ki) {
        const f32x4 s4 = sfr[qf][ki];
        const float p0 = exp2_fast(s4[0]);
        const float p1 = exp2_fast(s4[1]);
        const float p2 = exp2_fast(s4[2]);
        const float p3 = exp2_fast(s4[3]);
        rs += (p0 + p1) + (p2 + p3);
        pw[qf][ki * 2 + 0] = cvt_pk_bf16(p0, p1);
        pw[qf][ki * 2 + 1] = cvt_pk_bf16(p2, p3);
      }
      lrun[qf] += rs;
    }

    // O += P V per 32-k chunk: pf = pw words (A-operand, sigma-permuted);
    // vf = sigma-packed V granule (kkl*4+l4)^sw -> one b128, perm cancels.
#pragma unroll
    for (int kkl = 0; kkl < 2; ++kkl) {
      bf16x8 pf[4];
#pragma unroll
      for (int qf = 0; qf < 4; ++qf) {
        const u32x4 t = {pw[qf][kkl * 4 + 0], pw[qf][kkl * 4 + 1],
                         pw[qf][kkl * 4 + 2], pw[qf][kkl * 4 + 3]};
        pf[qf] = __builtin_bit_cast(bf16x8, t);
      }
      bf16x8 vf[4];
#pragma unroll
      for (int di = 0; di < 4; ++di)
        vf[di] = *(const bf16x8*)(Vb + (di * 16 + l15) * 64 +
                                  (((kkl * 4 + l4) ^ sw) << 3));
      __builtin_amdgcn_s_setprio(1);
#pragma unroll
      for (int di = 0; di < 4; ++di)
#pragma unroll
        for (int qf = 0; qf < 4; ++qf)
          O[di][qf] = __builtin_amdgcn_mfma_f32_16x16x32_bf16(pf[qf], vf[di], O[di][qf], 0, 0, 0);
      __builtin_amdgcn_s_setprio(0);
    }

    __builtin_amdgcn_s_barrier();     // all waves done reading slot
    if (j + 2 < 16) {
      STAGE(slot, j + 2);
      vmwait<8>();                    // tile j+1 (8 loads) landed
    } else {
      vmwait<0>();
    }
    __builtin_amdgcn_s_barrier();     // tile j+1 visible to all waves
  };

  STAGE(0, 0);
  STAGE(1, 1);
  vmwait<8>();
  __builtin_amdgcn_s_barrier();

  for (int jp = 0; jp < 8; ++jp) {    // slot literals -> const LDS bases
    DO_ITER(0, jp * 2);
    DO_ITER(1, jp * 2 + 1);
  }

  // parallel cross-spill merge: reuse Kt as f32 O-scratch (8 planes x 4KB),
  // Vt head as l-scratch. grp0 spills qf{2,3} -> planes 0..3 (bank A);
  // grp1 spills qf{0,1} -> planes 4..7 (bank B). After barrier, grp0
  // finalizes qf{0,1} (own regs + bank B), grp1 finalizes qf{2,3} (bank A).
  float* Osh = (float*)&Kt[0][0][0];
  float* lsh = (float*)&Vt[0][0][0];
  if (grp == 0) {
#pragma unroll
    for (int qq = 0; qq < 2; ++qq) {
      float* ob = Osh + (wg * 2 + qq) * 1024;
#pragma unroll
      for (int di = 0; di < 4; ++di)
#pragma unroll
        for (int jj = 0; jj < 4; ++jj)
          ob[(l4 * 4 + jj) * 64 + di * 16 + l15] = O[di][2 + qq][jj];
      lsh[(wg * 2 + qq) * 64 + l] = lrun[2 + qq];
    }
  } else {
#pragma unroll
    for (int qq = 0; qq < 2; ++qq) {
      float* ob = Osh + (4 + wg * 2 + qq) * 1024;
#pragma unroll
      for (int di = 0; di < 4; ++di)
#pragma unroll
        for (int jj = 0; jj < 4; ++jj)
          ob[(l4 * 4 + jj) * 64 + di * 16 + l15] = O[di][qq][jj];
      lsh[(4 + wg * 2 + qq) * 64 + l] = lrun[qq];
    }
  }
  __syncthreads();
  const int b = bh >> 4, hh = bh & 15;
  if (grp == 0) {
#pragma unroll
    for (int qq = 0; qq < 2; ++qq) {
      const float* obr = Osh + (4 + wg * 2 + qq) * 1024;
      float lt = lrun[qq] + lsh[(4 + wg * 2 + qq) * 64 + l];
      lt += __shfl_xor(lt, 16);
      lt += __shfl_xor(lt, 32);
      float lq[4];
#pragma unroll
      for (int jj = 0; jj < 4; ++jj)
        lq[jj] = __builtin_amdgcn_rcpf(__shfl(lt, l4 * 4 + jj));
#pragma unroll
      for (int di = 0; di < 4; ++di)
#pragma unroll
        for (int jj = 0; jj < 4; ++jj) {
          const float oval =
              (O[di][qq][jj] + obr[(l4 * 4 + jj) * 64 + di * 16 + l15]) * lq[jj];
          const int srw = qrow0 + qq * 16 + l4 * 4 + jj;
          const int c = hh * 64 + di * 16 + l15;
          po[((size_t)(b * 2048 + srw)) * 1024 + c] = f2bf(oval);
        }
    }
  } else {
#pragma unroll
    for (int qq = 0; qq < 2; ++qq) {
      const float* obr = Osh + (wg * 2 + qq) * 1024;
      float lt = lrun[2 + qq] + lsh[(wg * 2 + qq) * 64 + l];
      lt += __shfl_xor(lt, 16);
      lt += __shfl_xor(lt, 32);
      float lq[4];
#pragma unroll
      for (int jj = 0; jj < 4; ++jj)
        lq[jj] = __builtin_amdgcn_rcpf(__shfl(lt, l4 * 4 + jj));
#pragma unroll
      for (int di = 0; di < 4; ++di)
#pragma unroll
        for (int jj = 0; jj < 4; ++jj) {
          const float oval =
              (O[di][2 + qq][jj] + obr[(l4 * 4 + jj) * 64 + di * 16 + l15]) * lq[jj];
          const int srw = qrow0 + (2 + qq) * 16 + l4 * 4 + jj;
          const int c = hh * 64 + di * 16 + l15;
          po[((size_t)(b * 2048 + srw)) * 1024 + c] = f2bf(oval);
        }
    }
  }
}

// ---------------------------------------------------------------------------
extern "C" void kernel_launch(void* const* d_in, const int* in_sizes, int n_in,
                              void* d_out, int out_size, void* d_ws, size_t ws_size,
                              hipStream_t stream) {
  (void)in_sizes; (void)n_in; (void)out_size; (void)ws_size;
  const float* x  = (const float*)d_in[0];
  const float* wq = (const float*)d_in[1];
  const float* bq = (const float*)d_in[2];
  const float* wk = (const float*)d_in[3];
  const float* bk = (const float*)d_in[4];
  const float* wv = (const float*)d_in[5];
  const float* bv = (const float*)d_in[6];
  const float* wp = (const float*)d_in[7];
  const float* bp = (const float*)d_in[8];

  char* ws = (char*)d_ws;
  u16*   wquant = (u16*)ws;                   // [4][1024][1024] bf16 int levels, 8 MB
  float* scales = (float*)(ws + 8388608);     // [4][1024] f32, 16 KB
  u16*   xb     = (u16*)(ws + 8404992);       // [4096][1024] bf16 x (QKV input), 8 MB
  u16*   po     = xb;                         // [4096][1024] bf16 attn out (xb dead)
  u16*   qkv    = (u16*)(ws + 25182208);      // q,k:(b,h,s,d); v:(b,h,d,k') 24 MB

  prep_kernel<<<dim3(8192), dim3(256), 0, stream>>>(
      wq, wk, wv, wp, x, wquant, scales, xb);
  // QKV: 128x192 tile, K=1024 -> grid 512, 80 KB LDS
  gemm_kernel<0, 4, 3, 16, 16, 1024><<<dim3(512), dim3(512), 0, stream>>>(
      xb, wquant, scales, bq, bk, bv, qkv, nullptr);
  // attn: 2 KV-split groups x 2 waves x 64 q (QBLK=128), grid 512
  attn_kernel<<<dim3(512), dim3(256), 0, stream>>>(
      qkv, qkv + 4194304, qkv + 8388608, po);
  // proj: 64x128 tile, K=1024 (plain bf16 po) -> grid 512, 48 KB LDS
  gemm_kernel<1, 2, 2, 8, 16, 1024><<<dim3(512), dim3(512), 0, stream>>>(
      po, wquant + 3145728, scales + 3072, bp, nullptr, nullptr, nullptr, (float*)d_out);
}

// Round 21
// 95.899 us; speedup vs baseline: 1.2198x; 1.2198x over previous
//
#include <hip/hip_runtime.h>
#include <stdint.h>

typedef short bf16x8 __attribute__((ext_vector_type(8)));
typedef float f32x4 __attribute__((ext_vector_type(4)));
typedef uint16_t u16;
typedef uint32_t u32;
typedef u16 u16x4 __attribute__((ext_vector_type(4)));
typedef u32 u32x4 __attribute__((ext_vector_type(4)));

#define EPSF 1.1920929e-07f

static __device__ __forceinline__ u16 f2bf(float f) {
  union { float f; uint32_t u; } v; v.f = f;
  return (u16)((v.u + 0x7FFFu + ((v.u >> 16) & 1u)) >> 16);  // RNE
}
static __device__ __forceinline__ float bf2f(u16 h) {
  union { uint32_t u; float f; } v; v.u = ((uint32_t)h) << 16;
  return v.f;
}
static __device__ __forceinline__ float exp2_fast(float x) {
  return __builtin_amdgcn_exp2f(x);  // v_exp_f32: D = 2^S0
}
static __device__ __forceinline__ u32 cvt_pk_bf16(float lo, float hi) {
  u32 r;
  asm("v_cvt_pk_bf16_f32 %0, %1, %2" : "=v"(r) : "v"(lo), "v"(hi));
  return r;
}
static __device__ __forceinline__ void gload_lds16(const void* g, void* l) {
  __builtin_amdgcn_global_load_lds(
      (const __attribute__((address_space(1))) void*)g,
      (__attribute__((address_space(3))) void*)l, 16, 0, 0);
}
template <int N>
static __device__ __forceinline__ void vmwait() {
  asm volatile("s_waitcnt vmcnt(%0)" ::"i"(N) : "memory");
}

// ---------------------------------------------------------------------------
// 1) prep: fake-quant (blocks 0..4095) + x -> plain bf16 (blocks 4096..8191).
// ---------------------------------------------------------------------------
__global__ __launch_bounds__(256) void prep_kernel(
    const float* __restrict__ wq, const float* __restrict__ wk,
    const float* __restrict__ wv, const float* __restrict__ wp,
    const float* __restrict__ x,
    u16* __restrict__ wout, float* __restrict__ scales, u16* __restrict__ xb) {
  const int t = threadIdx.x;
  if (blockIdx.x < 4096) {
    const int row = blockIdx.x & 1023;
    const int mat = blockIdx.x >> 10;
    const float* W = (mat == 0) ? wq : (mat == 1) ? wk : (mat == 2) ? wv : wp;
    const float4 v = ((const float4*)(W + (size_t)row * 1024))[t];
    float m = fmaxf(fmaxf(fabsf(v.x), fabsf(v.y)), fmaxf(fabsf(v.z), fabsf(v.w)));
#pragma unroll
    for (int off = 1; off < 64; off <<= 1) m = fmaxf(m, __shfl_xor(m, off));
    __shared__ float red[4];
    if ((t & 63) == 0) red[t >> 6] = m;
    __syncthreads();
    m = fmaxf(fmaxf(red[0], red[1]), fmaxf(red[2], red[3]));
    const float scale = fmaxf(m / 127.0f, EPSF);
    float q0 = fminf(fmaxf(rintf(v.x / scale), -127.f), 127.f);
    float q1 = fminf(fmaxf(rintf(v.y / scale), -127.f), 127.f);
    float q2 = fminf(fmaxf(rintf(v.z / scale), -127.f), 127.f);
    float q3 = fminf(fmaxf(rintf(v.w / scale), -127.f), 127.f);
    u16x4 o; o.x = f2bf(q0); o.y = f2bf(q1); o.z = f2bf(q2); o.w = f2bf(q3);
    *(u16x4*)(wout + ((size_t)(mat * 1024 + row)) * 1024 + t * 4) = o;
    if (t == 0) scales[mat * 1024 + row] = scale;
  } else {
    const int i = (blockIdx.x - 4096) * 256 + t;  // quad index
    const float4 v = ((const float4*)x)[i];
    u16x4 hv;
    hv.x = f2bf(v.x); hv.y = f2bf(v.y); hv.z = f2bf(v.z); hv.w = f2bf(v.w);
    *(u16x4*)(xb + (size_t)i * 4) = hv;  // [4096][1024] row-major
  }
}

// ---------------------------------------------------------------------------
// 3) bf16 MFMA GEMM, counted-vmcnt pipeline. MODE 0: V written SIGMA-PACKED
//    per-bh ([64 d][2048 k], each 32-k chunk reordered pos = l4k*8+hi*4+j
//    for k = hi*16+l4k*4+j) so attn's PV B-fragment is one contiguous b128.
// ---------------------------------------------------------------------------
template <int MODE, int MR, int NR, int NT, int KT, int LDA>
__global__ __launch_bounds__(512) void gemm_kernel(
    const u16* __restrict__ A, const u16* __restrict__ Bw,
    const float* __restrict__ scales, const float* __restrict__ b0,
    const float* __restrict__ b1, const float* __restrict__ b2,
    u16* __restrict__ qkv, float* __restrict__ outp) {
  constexpr int BM = 2 * MR * 16;
  constexpr int BN = 4 * NR * 16;
  constexpr int OPS = BM / 64 + BN / 64;  // gload_lds per thread per K-tile
  __shared__ u16 As[2][BM * 64];
  __shared__ u16 Bs[2][BN * 64];
  const int tid = threadIdx.x;
  const int w = tid >> 6, l = tid & 63;
  const int per = gridDim.x >> 3;
  const int L = (blockIdx.x & 7) * per + (blockIdx.x >> 3);
  const int tile_n = (L % NT) * BN;
  const int tile_m = (L / NT) * BM;
  const int wm = w >> 2, wn = w & 3;
  const int l15 = l & 15, l4 = l >> 4;
  const int sw = l15 & 7;

  f32x4 acc[MR][NR];
  const f32x4 vzero = {0.f, 0.f, 0.f, 0.f};
#pragma unroll
  for (int m = 0; m < MR; ++m)
#pragma unroll
    for (int n = 0; n < NR; ++n) acc[m][n] = vzero;

  const int r8 = tid >> 3;          // 0..63
  const int g = tid & 7;
  const int gs = g ^ (r8 & 7);      // pre-swizzled source granule
  auto STAGE = [&](int slot, int j) {
    const int kb = j * 64;
    const int kbB = kb & 1023;
#pragma unroll
    for (int i = 0; i < BM / 64; ++i)
      gload_lds16(A + (size_t)(tile_m + i * 64 + r8) * LDA + kb + gs * 8,
                  &As[slot][(i * 64 + r8) * 64 + g * 8]);
#pragma unroll
    for (int i = 0; i < BN / 64; ++i)
      gload_lds16(Bw + (size_t)(tile_n + i * 64 + r8) * 1024 + kbB + gs * 8,
                  &Bs[slot][(i * 64 + r8) * 64 + g * 8]);
  };

  STAGE(0, 0);
  STAGE(1, 1);
  vmwait<OPS>();                      // K0 landed; K1 still in flight
  __builtin_amdgcn_s_barrier();

  for (int j = 0; j < KT; ++j) {
    const int cur = j & 1;
#pragma unroll
    for (int ks = 0; ks < 2; ++ks) {
      bf16x8 af[MR], bfv[NR];
      const int sg8 = ((ks * 4 + l4) ^ sw) * 8;
#pragma unroll
      for (int m = 0; m < MR; ++m)
        af[m] = *(const bf16x8*)(&As[cur][(wm * (MR * 16) + m * 16 + l15) * 64 + sg8]);
#pragma unroll
      for (int n = 0; n < NR; ++n)
        bfv[n] = *(const bf16x8*)(&Bs[cur][(wn * (NR * 16) + n * 16 + l15) * 64 + sg8]);
      __builtin_amdgcn_s_setprio(1);
#pragma unroll
      for (int m = 0; m < MR; ++m)
#pragma unroll
        for (int n = 0; n < NR; ++n)
          acc[m][n] = __builtin_amdgcn_mfma_f32_16x16x32_bf16(af[m], bfv[n], acc[m][n], 0, 0, 0);
      __builtin_amdgcn_s_setprio(0);
    }
    __builtin_amdgcn_s_barrier();     // all waves done reading slot cur
    if (j + 2 < KT) {
      STAGE(cur, j + 2);
      vmwait<OPS>();                  // K_{j+1} landed; K_{j+2} in flight
    } else {
      vmwait<0>();
    }
    __builtin_amdgcn_s_barrier();     // K_{j+1} visible to all waves
  }

#pragma unroll
  for (int m = 0; m < MR; ++m) {
#pragma unroll
    for (int n = 0; n < NR; ++n) {
      const int col = tile_n + wn * (NR * 16) + n * 16 + l15;
      const float sc = scales[col];
      if constexpr (MODE == 0) {
        const int mat = col >> 10, oo = col & 1023;
        const float* bias = (mat == 0) ? b0 : (mat == 1) ? b1 : b2;
        const float bb = bias[oo];
        const int hh = oo >> 6, dd = oo & 63;
        if (mat == 2) {
          // V' sigma-packed: [bh][64 d][2048 k']; within each 32-k chunk,
          // pos = ((k>>2)&3)*8 + ((k>>4)&1)*4 + (k&3). The lane's 4
          // consecutive k (s0..s0+3, s0%4==0) stay one contiguous u16x4.
          const int rowm0 = tile_m + wm * (MR * 16) + m * 16 + l4 * 4;
          const int b = rowm0 >> 11, s = rowm0 & 2047;
          u16x4 pk;
#pragma unroll
          for (int jj = 0; jj < 4; ++jj) pk[jj] = f2bf(acc[m][n][jj] * sc + bb);
          const int kpos = (s & ~31) + ((s >> 2) & 3) * 8 + ((s >> 4) & 1) * 4;
          *(u16x4*)(qkv + (size_t)2 * 4194304 +
                    ((size_t)(b * 16 + hh) * 64 + dd) * 2048 + kpos) = pk;
        } else {
#pragma unroll
          for (int jj = 0; jj < 4; ++jj) {
            const int rowm = tile_m + wm * (MR * 16) + m * 16 + l4 * 4 + jj;
            const int b = rowm >> 11, s = rowm & 2047;
            float y = acc[m][n][jj] * sc + bb;
            if (mat == 0) y *= 0.18033688011112042f;  // 0.125*log2(e)
            qkv[(size_t)mat * 4194304 + ((size_t)(b * 16 + hh) * 2048 + s) * 64 + dd] = f2bf(y);
          }
        }
      } else {
        const float bb = b0[col];
#pragma unroll
        for (int jj = 0; jj < 4; ++jj) {
          const int rowm = tile_m + wm * (MR * 16) + m * 16 + l4 * 4 + jj;
          outp[(size_t)rowm * 1024 + col] = acc[m][n][jj] * sc + bb;
        }
      }
    }
  }
}

// ---------------------------------------------------------------------------
// 4) Flash attention v17 (= R19 v15, the best-measured config, + zero-init
//    removal: dk=0 MFMA writes sfr with C-in = 0 directly):
//    KV-split two-barrier schedule, 2 groups x 4 waves x 32 q, KVBLK=64,
//    prefetch distance 2, sigma-packed V -> one b128 per PV fragment,
//    no-max exp2 softmax, XCD-chunk swizzle, parallel merge epilogue.
// ---------------------------------------------------------------------------
__global__ __launch_bounds__(512, 4) void attn_kernel(
    const u16* __restrict__ qg, const u16* __restrict__ kg,
    const u16* __restrict__ vtg, u16* __restrict__ po) {
  __shared__ u16 Kt[2][2][64 * 64];     // [slot][group][k][d], swizzled
  __shared__ u16 Vt[2][2][64 * 64];     // [slot][group][d][k'], swizzled
  const int tid = threadIdx.x;
  const int w = tid >> 6, l = tid & 63;
  const int Lb = (blockIdx.x & 7) * 64 + (blockIdx.x >> 3);  // XCD chunk
  const int bh = Lb >> 4;
  const int qt = Lb & 15;
  const u16* qp = qg + (size_t)bh * 131072;
  const u16* kp = kg + (size_t)bh * 131072;
  const u16* vp = vtg + (size_t)bh * 131072;  // V' [64][2048] sigma-packed
  const int wg = w & 3, grp = w >> 2;
  const int qrow0 = qt * 128 + wg * 32;
  const int l15 = l & 15, l4 = l >> 4;
  const int sw = l15 & 7;

  // stage both groups' K/V tiles; linear LDS dest, swizzled GLOBAL source
  const int sr = tid >> 3, sg = tid & 7;
  const int gsw = (sg ^ (sr & 7)) << 3;
  auto STAGE = [&](const int slot, const int j) {
    const int kA = j * 64, kB = 1024 + j * 64;
    gload_lds16(kp + (size_t)(kA + sr) * 64 + gsw, &Kt[slot][0][tid * 8]);
    gload_lds16(vp + (size_t)sr * 2048 + kA + gsw, &Vt[slot][0][tid * 8]);
    gload_lds16(kp + (size_t)(kB + sr) * 64 + gsw, &Kt[slot][1][tid * 8]);
    gload_lds16(vp + (size_t)sr * 2048 + kB + gsw, &Vt[slot][1][tid * 8]);
  };

  bf16x8 qfr[2][2];  // [dk][qf]
#pragma unroll
  for (int dk = 0; dk < 2; ++dk)
#pragma unroll
    for (int qf = 0; qf < 2; ++qf)
      qfr[dk][qf] =
          *(const bf16x8*)(qp + (size_t)(qrow0 + qf * 16 + l15) * 64 + dk * 32 + l4 * 8);

  const f32x4 vzero = {0.f, 0.f, 0.f, 0.f};
  f32x4 O[4][2];
#pragma unroll
  for (int di = 0; di < 4; ++di)
#pragma unroll
    for (int qf = 0; qf < 2; ++qf) O[di][qf] = vzero;
  float lrun[2] = {0.f, 0.f};       // per-lane partial row sums

  // one iteration per group-local 64-k tile; slot LITERAL at call sites
  auto DO_ITER = [&](const int slot, const int j) {
    const u16* Kb = &Kt[slot][grp][0];
    const u16* Vb = &Vt[slot][grp][0];

    // S^T = K Q^T over 64 k: D[k][q], k = ki*16 + l4*4 + jj, q = l15 (+qf*16)
    // dk=0 pass initializes sfr via C-in = 0 (no explicit zero-init).
    f32x4 sfr[2][4];  // [qf][ki]
    {
      bf16x8 kf[4];
#pragma unroll
      for (int ki = 0; ki < 4; ++ki)
        kf[ki] = *(const bf16x8*)(Kb + (ki * 16 + l15) * 64 + ((l4 ^ sw) << 3));
      __builtin_amdgcn_s_setprio(1);
#pragma unroll
      for (int ki = 0; ki < 4; ++ki)
#pragma unroll
        for (int qf = 0; qf < 2; ++qf)
          sfr[qf][ki] = __builtin_amdgcn_mfma_f32_16x16x32_bf16(kf[ki], qfr[0][qf], vzero, 0, 0, 0);
      __builtin_amdgcn_s_setprio(0);
    }
    {
      bf16x8 kf[4];
#pragma unroll
      for (int ki = 0; ki < 4; ++ki)
        kf[ki] = *(const bf16x8*)(Kb + (ki * 16 + l15) * 64 + (((4 + l4) ^ sw) << 3));
      __builtin_amdgcn_s_setprio(1);
#pragma unroll
      for (int ki = 0; ki < 4; ++ki)
#pragma unroll
        for (int qf = 0; qf < 2; ++qf)
          sfr[qf][ki] = __builtin_amdgcn_mfma_f32_16x16x32_bf16(kf[ki], qfr[1][qf], sfr[qf][ki], 0, 0, 0);
      __builtin_amdgcn_s_setprio(0);
    }

    // no-max softmax: p = exp2(S); P stays in registers
    u32 pw[2][8];
#pragma unroll
    for (int qf = 0; qf < 2; ++qf) {
      float rs = 0.f;
#pragma unroll
      for (int ki = 0; ki < 4; ++ki) {
        const f32x4 s4 = sfr[qf][ki];
        const float p0 = exp2_fast(s4[0]);
        const float p1 = exp2_fast(s4[1]);
        const float p2 = exp2_fast(s4[2]);
        const float p3 = exp2_fast(s4[3]);
        rs += (p0 + p1) + (p2 + p3);
        pw[qf][ki * 2 + 0] = cvt_pk_bf16(p0, p1);
        pw[qf][ki * 2 + 1] = cvt_pk_bf16(p2, p3);
      }
      lrun[qf] += rs;
    }

    // O += P V per 32-k chunk: pf = pw words (A-operand, sigma-permuted);
    // vf = sigma-packed V granule (kkl*4+l4)^sw -> one b128, perm cancels.
#pragma unroll
    for (int kkl = 0; kkl < 2; ++kkl) {
      const u32x4 t0 = {pw[0][kkl * 4 + 0], pw[0][kkl * 4 + 1],
                        pw[0][kkl * 4 + 2], pw[0][kkl * 4 + 3]};
      const u32x4 t1 = {pw[1][kkl * 4 + 0], pw[1][kkl * 4 + 1],
                        pw[1][kkl * 4 + 2], pw[1][kkl * 4 + 3]};
      const bf16x8 pf0 = __builtin_bit_cast(bf16x8, t0);
      const bf16x8 pf1 = __builtin_bit_cast(bf16x8, t1);
      bf16x8 vf[4];
#pragma unroll
      for (int di = 0; di < 4; ++di)
        vf[di] = *(const bf16x8*)(Vb + (di * 16 + l15) * 64 +
                                  (((kkl * 4 + l4) ^ sw) << 3));
      __builtin_amdgcn_s_setprio(1);
#pragma unroll
      for (int di = 0; di < 4; ++di) {
        O[di][0] = __builtin_amdgcn_mfma_f32_16x16x32_bf16(pf0, vf[di], O[di][0], 0, 0, 0);
        O[di][1] = __builtin_amdgcn_mfma_f32_16x16x32_bf16(pf1, vf[di], O[di][1], 0, 0, 0);
      }
      __builtin_amdgcn_s_setprio(0);
    }

    __builtin_amdgcn_s_barrier();     // all waves done reading slot
    if (j + 2 < 16) {
      STAGE(slot, j + 2);
      vmwait<4>();                    // tile j+1 (4 loads) landed
    } else {
      vmwait<0>();
    }
    __builtin_amdgcn_s_barrier();     // tile j+1 visible to all waves
  };

  STAGE(0, 0);
  STAGE(1, 1);
  vmwait<4>();
  __builtin_amdgcn_s_barrier();

  for (int jp = 0; jp < 8; ++jp) {    // slot literals -> const LDS bases
    DO_ITER(0, jp * 2);
    DO_ITER(1, jp * 2 + 1);
  }

  // parallel merge: reuse Kt as f32 O-scratch, Vt head as l-scratch.
  // grp1 spills qf0 (planes 0..3); grp0 spills qf1 (planes 4..7).
  // Then grp0 finalizes qf0, grp1 finalizes qf1 (both groups write po).
  float* Osh = (float*)&Kt[0][0][0];  // 8 planes x 1024 f32 = 32 KB
  float* lsh = (float*)&Vt[0][0][0];  // 8 x 64 f32
  if (grp == 1) {
    float* ob = Osh + (0 * 4 + wg) * 1024;
#pragma unroll
    for (int di = 0; di < 4; ++di)
#pragma unroll
      for (int jj = 0; jj < 4; ++jj)
        ob[(l4 * 4 + jj) * 64 + di * 16 + l15] = O[di][0][jj];
    lsh[(0 * 4 + wg) * 64 + l] = lrun[0];
  } else {
    float* ob = Osh + (1 * 4 + wg) * 1024;
#pragma unroll
    for (int di = 0; di < 4; ++di)
#pragma unroll
      for (int jj = 0; jj < 4; ++jj)
        ob[(l4 * 4 + jj) * 64 + di * 16 + l15] = O[di][1][jj];
    lsh[(1 * 4 + wg) * 64 + l] = lrun[1];
  }
  __syncthreads();
  const int b = bh >> 4, hh = bh & 15;
  if (grp == 0) {
    const float* obr = Osh + (0 * 4 + wg) * 1024;
    float lt = lrun[0] + lsh[(0 * 4 + wg) * 64 + l];
    lt += __shfl_xor(lt, 16);
    lt += __shfl_xor(lt, 32);
    float lq[4];
#pragma unroll
    for (int jj = 0; jj < 4; ++jj)
      lq[jj] = __builtin_amdgcn_rcpf(__shfl(lt, l4 * 4 + jj));
#pragma unroll
    for (int di = 0; di < 4; ++di)
#pragma unroll
      for (int jj = 0; jj < 4; ++jj) {
        const float oval =
            (O[di][0][jj] + obr[(l4 * 4 + jj) * 64 + di * 16 + l15]) * lq[jj];
        const int srw = qrow0 + l4 * 4 + jj;
        const int c = hh * 64 + di * 16 + l15;
        po[((size_t)(b * 2048 + srw)) * 1024 + c] = f2bf(oval);
      }
  } else {
    const float* obr = Osh + (1 * 4 + wg) * 1024;
    float lt = lrun[1] + lsh[(1 * 4 + wg) * 64 + l];
    lt += __shfl_xor(lt, 16);
    lt += __shfl_xor(lt, 32);
    float lq[4];
#pragma unroll
    for (int jj = 0; jj < 4; ++jj)
      lq[jj] = __builtin_amdgcn_rcpf(__shfl(lt, l4 * 4 + jj));
#pragma unroll
    for (int di = 0; di < 4; ++di)
#pragma unroll
      for (int jj = 0; jj < 4; ++jj) {
        const float oval =
            (O[di][1][jj] + obr[(l4 * 4 + jj) * 64 + di * 16 + l15]) * lq[jj];
        const int srw = qrow0 + 16 + l4 * 4 + jj;
        const int c = hh * 64 + di * 16 + l15;
        po[((size_t)(b * 2048 + srw)) * 1024 + c] = f2bf(oval);
      }
  }
}

// ---------------------------------------------------------------------------
extern "C" void kernel_launch(void* const* d_in, const int* in_sizes, int n_in,
                              void* d_out, int out_size, void* d_ws, size_t ws_size,
                              hipStream_t stream) {
  (void)in_sizes; (void)n_in; (void)out_size; (void)ws_size;
  const float* x  = (const float*)d_in[0];
  const float* wq = (const float*)d_in[1];
  const float* bq = (const float*)d_in[2];
  const float* wk = (const float*)d_in[3];
  const float* bk = (const float*)d_in[4];
  const float* wv = (const float*)d_in[5];
  const float* bv = (const float*)d_in[6];
  const float* wp = (const float*)d_in[7];
  const float* bp = (const float*)d_in[8];

  char* ws = (char*)d_ws;
  u16*   wquant = (u16*)ws;                   // [4][1024][1024] bf16 int levels, 8 MB
  float* scales = (float*)(ws + 8388608);     // [4][1024] f32, 16 KB
  u16*   xb     = (u16*)(ws + 8404992);       // [4096][1024] bf16 x (QKV input), 8 MB
  u16*   po     = xb;                         // [4096][1024] bf16 attn out (xb dead)
  u16*   qkv    = (u16*)(ws + 25182208);      // q,k:(b,h,s,d); v:(b,h,d,k') 24 MB

  prep_kernel<<<dim3(8192), dim3(256), 0, stream>>>(
      wq, wk, wv, wp, x, wquant, scales, xb);
  // QKV: 128x192 tile, K=1024 -> grid 512, 80 KB LDS
  gemm_kernel<0, 4, 3, 16, 16, 1024><<<dim3(512), dim3(512), 0, stream>>>(
      xb, wquant, scales, bq, bk, bv, qkv, nullptr);
  // attn: QBLK=128 (2 KV-split groups of 4 waves x 32 q), grid 512
  attn_kernel<<<dim3(512), dim3(512), 0, stream>>>(
      qkv, qkv + 4194304, qkv + 8388608, po);
  // proj: 64x128 tile, K=1024 (plain bf16 po) -> grid 512, 48 KB LDS
  gemm_kernel<1, 2, 2, 8, 16, 1024><<<dim3(512), dim3(512), 0, stream>>>(
      po, wquant + 3145728, scales + 3072, bp, nullptr, nullptr, nullptr, (float*)d_out);
}